// Round 8
// baseline (729.570 us; speedup 1.0000x reference)
//
#include <hip/hip_runtime.h>
#include <hip/hip_bf16.h>
#include <math.h>

// CRF forward, B=512,S=512,C=96. ONE 64-lane wave per 16 chains (32 blocks).
// Step for 16 chains = (16x96)·(96x96) matmul via 18x mfma_f32_16x16x32_f16.
// E=exp(T) lives in B-frags (MFMA reads AGPRs natively -> no copy tax).
// State = f16 A-frags, exactly power-of-2 normalized per chain per step;
// integer exponent sum S[c] is exact. exp(em) prefetched distance 2 and
// computed on the VALU pipe (co-issues with MFMA). C->A layout transform
// through LDS; single wave => in-order DS pipe => NO barriers at all.
//
// Layouts (gfx950, verified in guide): C/D: col=lane&15, row=(lane>>4)*4+reg.
// A: m=lane&15, k=(lane>>4)*8+j. B assumed symmetric: n=lane&15, k=(lane>>4)*8+j.

#define BATCH 512
#define SEQ   512
#define NC    96
#define CH    16
#define NBLK  (BATCH / CH)   // 32
#define PAD   104            // halves per chain row in LDS (16B-aligned rows)
#define LN2   0.69314718055994531f
#define LN2X4 2.7725887222397812f

typedef __fp16 half2v __attribute__((ext_vector_type(2)));
typedef __fp16 half8v __attribute__((ext_vector_type(8)));
typedef float  f32x4  __attribute__((ext_vector_type(4)));

#define DPP_STEP_F(v, op, ctrl)                                              \
    v = op(v, __int_as_float(__builtin_amdgcn_update_dpp(                    \
            __float_as_int(v), __float_as_int(v), (ctrl), 0xf, 0xf, false)))

__device__ __forceinline__ float fadd_(float a, float b) { return a + b; }
__device__ __forceinline__ float wave_sum_all(float v) {
    DPP_STEP_F(v, fadd_, 0x111);
    DPP_STEP_F(v, fadd_, 0x112);
    DPP_STEP_F(v, fadd_, 0x114);
    DPP_STEP_F(v, fadd_, 0x118);
    DPP_STEP_F(v, fadd_, 0x142);
    DPP_STEP_F(v, fadd_, 0x143);
    return __int_as_float(__builtin_amdgcn_readlane(__float_as_int(v), 63));
}
__device__ __forceinline__ float bperm_f(int lanesrc, float v) {
    return __int_as_float(__builtin_amdgcn_ds_bpermute(
        (lanesrc & 63) << 2, __float_as_int(v)));
}
__device__ __forceinline__ int bperm_i(int lanesrc, int v) {
    return __builtin_amdgcn_ds_bpermute((lanesrc & 63) << 2, v);
}

__global__ __launch_bounds__(64, 1)
void crf_llh_kernel(const float* __restrict__ em,      // (B,S,C)
                    const int*   __restrict__ tags,    // (B,S)
                    const int*   __restrict__ masks,   // (B,S)
                    const float* __restrict__ startT,  // (C)
                    const float* __restrict__ endT,    // (C)
                    const float* __restrict__ trans,   // (C,C)
                    float*       __restrict__ out)     // scalar
{
    const int b = blockIdx.x;
    const int l = threadIdx.x;      // 0..63
    const int c = l & 15;
    const int q = l >> 4;

    __shared__ __fp16 wl[CH * PAD];   // w matrix, row-major [chain][k]
    __shared__ float  maxsh[CH];      // per-chain step max (fp32)

    // ---- B-frags: E[k][n] = exp(trans[k][n]); B: n=c, k=32*kt+8*q+j ----
    half8v Bf[3][6];
    #pragma unroll
    for (int kt = 0; kt < 3; ++kt) {
        #pragma unroll
        for (int nt = 0; nt < 6; ++nt) {
            #pragma unroll
            for (int jp = 0; jp < 4; ++jp) {
                const int k0 = 32 * kt + 8 * q + 2 * jp;
                const int n  = 16 * nt + c;
                const half2v pe = __builtin_amdgcn_cvt_pkrtz(
                    __expf(trans[(k0)     * NC + n]),
                    __expf(trans[(k0 + 1) * NC + n]));
                Bf[kt][nt][2 * jp]     = pe[0];
                Bf[kt][nt][2 * jp + 1] = pe[1];
            }
        }
    }

    // ---- init: alpha0 = start + em[.,0,.]; exact per-chain max M0 ----
    const size_t gc = (size_t)(b * CH + c);        // reader-side chain
    const float* em_c = em + gc * SEQ * NC;
    const int*   mk_c = masks + gc * SEQ;
    const int*   tg_c = tags  + gc * SEQ;

    half8v Af[3];
    float M0;
    int   S;
    {
        float a0[24];
        float mx = -1e30f;
        #pragma unroll
        for (int kt = 0; kt < 3; ++kt)
            #pragma unroll
            for (int j = 0; j < 8; ++j) {
                const int k = 32 * kt + 8 * q + j;
                const float v = startT[k] + em_c[k];
                a0[kt * 8 + j] = v;
                mx = fmaxf(mx, v);
            }
        mx = fmaxf(mx, bperm_f(l ^ 16, mx));
        mx = fmaxf(mx, bperm_f(l ^ 32, mx));
        M0 = mx;
        S  = 1;   // a = exp(alpha0-M0)*2^-1, so alpha = log a + M0 + S*ln2
        #pragma unroll
        for (int kt = 0; kt < 3; ++kt)
            #pragma unroll
            for (int j = 0; j < 8; ++j)
                Af[kt][j] = (__fp16)(__expf(a0[kt * 8 + j] - M0) * 0.5f);
    }

    // ---- writer-side emission bases (C-layout rows: chain = 4q+r) ----
    size_t emb[4];
    #pragma unroll
    for (int r = 0; r < 4; ++r)
        emb[r] = (size_t)(b * CH + 4 * q + r) * SEQ * NC + c;

    // prefetch distance 2
    float emA[24], emB[24];
    #pragma unroll
    for (int nt = 0; nt < 6; ++nt)
        #pragma unroll
        for (int r = 0; r < 4; ++r) {
            emA[nt * 4 + r] = em[emb[r] + (size_t)1 * NC + 16 * nt];
            emB[nt * 4 + r] = em[emb[r] + (size_t)2 * NC + 16 * nt];
        }
    int mkA = mk_c[1], mkB = mk_c[2];

    for (int s = 1; s < SEQ; ++s) {
        const int sp = (s + 2 < SEQ) ? (s + 2) : (SEQ - 1);
        float emN[24];
        #pragma unroll
        for (int nt = 0; nt < 6; ++nt)
            #pragma unroll
            for (int r = 0; r < 4; ++r)
                emN[nt * 4 + r] = em[emb[r] + (size_t)sp * NC + 16 * nt];
        const int mkN = mk_c[sp];

        // F = exp(em)*2^-4 (headroom) -- VALU, co-issues with MFMA
        float Fv[24];
        #pragma unroll
        for (int i = 0; i < 24; ++i) Fv[i] = __expf(emA[i] - LN2X4);

        // ---- MFMA: U(16x96) = A(16x96)·E(96x96), then w = U*F -> LDS f16
        float mr[4] = {-1e30f, -1e30f, -1e30f, -1e30f};
        #pragma unroll
        for (int nt = 0; nt < 6; ++nt) {
            f32x4 a = {0.f, 0.f, 0.f, 0.f};
            a = __builtin_amdgcn_mfma_f32_16x16x32_f16(Af[0], Bf[0][nt], a, 0, 0, 0);
            a = __builtin_amdgcn_mfma_f32_16x16x32_f16(Af[1], Bf[1][nt], a, 0, 0, 0);
            a = __builtin_amdgcn_mfma_f32_16x16x32_f16(Af[2], Bf[2][nt], a, 0, 0, 0);
            #pragma unroll
            for (int r = 0; r < 4; ++r) {
                const float wv = a[r] * Fv[nt * 4 + r];
                mr[r] = fmaxf(mr[r], wv);
                wl[(4 * q + r) * PAD + 16 * nt + c] = (__fp16)wv;   // ds_write_b16
            }
        }

        // per-chain max: DPP reduce within the 16-lane row; lane c==15 owns it
        #pragma unroll
        for (int r = 0; r < 4; ++r) {
            float v = mr[r];
            DPP_STEP_F(v, fmaxf, 0x111);
            DPP_STEP_F(v, fmaxf, 0x112);
            DPP_STEP_F(v, fmaxf, 0x114);
            DPP_STEP_F(v, fmaxf, 0x118);
            if (c == 15) maxsh[4 * q + r] = v;
        }

        // ---- read back in A-layout (chain = c); DS pipe is in-order for a
        // single wave: these reads see this step's writes, and the NEXT
        // step's writes (program-order later) cannot pass them. No barrier.
        const float mxc = maxsh[c];
        half8v A0 = *(const half8v*)&wl[c * PAD + 0  + q * 8];
        half8v A1 = *(const half8v*)&wl[c * PAD + 32 + q * 8];
        half8v A2 = *(const half8v*)&wl[c * PAD + 64 + q * 8];

        // exact power-of-2 renorm: scale = 2^-eb so max(a) in [0.5,1)
        const int eb = (int)((__float_as_uint(mxc) >> 23) & 255u) - 126;
        unsigned hbits = ((unsigned)(15 - eb)) << 10;   // f16 2^-eb
        hbits |= hbits << 16;
        const half2v sc2 = __builtin_bit_cast(half2v, hbits);

        half8v An[3] = {A0, A1, A2};
        #pragma unroll
        for (int kt = 0; kt < 3; ++kt) {
            #pragma unroll
            for (int jp = 0; jp < 4; ++jp) {
                half2v t = {An[kt][2 * jp], An[kt][2 * jp + 1]};
                t = t * sc2;                             // v_pk_mul_f16, exact
                An[kt][2 * jp]     = t[0];
                An[kt][2 * jp + 1] = t[1];
            }
        }
        if (mkA) {
            Af[0] = An[0]; Af[1] = An[1]; Af[2] = An[2];
            S += eb + 4;     // +4 from the 2^-4 folded into F
        }

        #pragma unroll
        for (int i = 0; i < 24; ++i) { emA[i] = emB[i]; emB[i] = emN[i]; }
        mkA = mkB; mkB = mkN;
    }

    // ---- denominator: M0 + S*ln2 + log(sum_j a_j * exp(end_j)) ----
    float dsum = 0.f;
    #pragma unroll
    for (int kt = 0; kt < 3; ++kt)
        #pragma unroll
        for (int j = 0; j < 8; ++j) {
            const int k = 32 * kt + 8 * q + j;
            dsum += (float)Af[kt][j] * __expf(endT[k]);
        }
    dsum += bperm_f(l ^ 16, dsum);
    dsum += bperm_f(l ^ 32, dsum);
    const float denom = M0 + (float)S * LN2 + __logf(dsum);

    // ---- numerator: tag-path gather; lane (c,q) does s in [128q,128q+128)
    float nsum = 0.f;
    int   cnt  = 0;
    {
        const int s0 = q * 128;
        int tprev = (s0 > 0) ? tg_c[s0 - 1] : 0;
        for (int i = 0; i < 128; ++i) {
            const int s  = s0 + i;
            const int tg = tg_c[s];
            const int mk = mk_c[s];
            cnt += mk ? 1 : 0;
            if (s == 0) {
                nsum += startT[tg] + em_c[tg];
            } else if (mk) {
                nsum += trans[tprev * NC + tg] + em_c[(size_t)s * NC + tg];
            }
            tprev = tg;
        }
    }
    nsum += bperm_f(l ^ 16, nsum);
    nsum += bperm_f(l ^ 32, nsum);
    cnt  += bperm_i(l ^ 16, cnt);
    cnt  += bperm_i(l ^ 32, cnt);

    float llh = 0.f;
    if (q == 0) {
        const int last = tg_c[cnt - 1];
        llh = (nsum + endT[last]) - denom;
    }
    const float tot = wave_sum_all(llh);
    if (l == 0) atomicAdd(out, tot * (1.0f / (float)BATCH));
}

extern "C" void kernel_launch(void* const* d_in, const int* in_sizes, int n_in,
                              void* d_out, int out_size, void* d_ws, size_t ws_size,
                              hipStream_t stream) {
    const float* em     = (const float*)d_in[0];
    const int*   tags   = (const int*)  d_in[1];
    const int*   masks  = (const int*)  d_in[2];
    const float* startT = (const float*)d_in[3];
    const float* endT   = (const float*)d_in[4];
    const float* trans  = (const float*)d_in[5];
    float* out = (float*)d_out;

    (void)hipMemsetAsync(out, 0, sizeof(float), stream);
    crf_llh_kernel<<<NBLK, 64, 0, stream>>>(em, tags, masks, startT, endT, trans, out);
}